// Round 2
// baseline (11263.465 us; speedup 1.0000x reference)
//
#include <hip/hip_runtime.h>
#include <hip/hip_bf16.h>
#include <cstdint>
#include <cstddef>

typedef unsigned short u16;
typedef __attribute__((ext_vector_type(4))) float f32x4;
typedef __attribute__((ext_vector_type(8))) short short8;

#define B_SZ 256
#define T_SZ 256
#define IN_SZ 64
#define H_SZ 512
#define G3 1536   // 3*H

__device__ __forceinline__ float bf2f(u16 u) {
  union { unsigned int i; float f; } v; v.i = ((unsigned int)u) << 16; return v.f;
}
__device__ __forceinline__ u16 f2bf(float f) {
  union { float f; unsigned int i; } v; v.f = f;
  unsigned int x = v.i;
  unsigned int r = (x + 0x7fffu + ((x >> 16) & 1u)) >> 16;  // RNE
  return (u16)r;
}
__device__ __forceinline__ float sigmoidf_(float x) { return 1.0f / (1.0f + __expf(-x)); }
__device__ __forceinline__ float tanhf_(float x) {
  float e = __expf(-2.0f * x); return (1.0f - e) / (1.0f + e);
}
__device__ __forceinline__ void gl_lds16(const void* g, void* l) {
  __builtin_amdgcn_global_load_lds(
      (const __attribute__((address_space(1))) unsigned int*)g,
      (__attribute__((address_space(3))) unsigned int*)l, 16, 0, 0);
}

// ---------------- weight-norm + bf16 cast: one wave per row ----------------
__global__ __launch_bounds__(256)
void norm_cast_kernel(const float* __restrict__ v, const float* __restrict__ g,
                      u16* __restrict__ out, int cols) {
  int row = blockIdx.x * 4 + (threadIdx.x >> 6);
  int lane = threadIdx.x & 63;
  const float* vr = v + (size_t)row * cols;
  float s = 0.f;
  for (int c = lane; c < cols; c += 64) { float t = vr[c]; s += t * t; }
  for (int o = 32; o; o >>= 1) s += __shfl_xor(s, o);
  float scale = g[row] / sqrtf(s);
  for (int c = lane; c < cols; c += 64) out[(size_t)row * cols + c] = f2bf(vr[c] * scale);
}

// cast x chunk [B, t0:t0+Tc, 64] fp32 -> chunk-local bf16 [B, Tc, 64]
__global__ __launch_bounds__(256)
void castx_kernel(const float* __restrict__ x, u16* __restrict__ xb, int t0, int Tc) {
  int i = blockIdx.x * 256 + threadIdx.x;   // float4 index in chunk
  int b = i / (Tc * 16); int rem = i % (Tc * 16);
  int tt = rem / 16;     int k4 = rem % 16;
  float4 v = ((const float4*)x)[(size_t)(b * T_SZ + t0 + tt) * 16 + k4];
  ushort4 o;
  o.x = f2bf(v.x); o.y = f2bf(v.y); o.z = f2bf(v.z); o.w = f2bf(v.w);
  ((ushort4*)xb)[i] = o;
}

// ---------------- tiled MFMA GEMM: C[M,1536] = A[M,K] * B[1536,K]^T + bias --
// 128x128 tile, BK=64, 4 waves, XOR-swizzled LDS via pre-swizzled global src.
template<bool GX32>
__global__ __launch_bounds__(256)
void gemm_kernel(const u16* __restrict__ A, const u16* __restrict__ Bm,
                 const float* __restrict__ bias, void* __restrict__ C, int K) {
  __shared__ u16 As[128 * 64];
  __shared__ u16 Bs[128 * 64];
  const int tid = threadIdx.x;
  const int lane = tid & 63;
  const int wv = tid >> 6;
  const int wm = wv >> 1, wn = wv & 1;
  const size_t arow0 = (size_t)blockIdx.y * 128;
  const size_t brow0 = (size_t)blockIdx.x * 128;
  f32x4 acc[4][4] = {};
  for (int ko = 0; ko < K; ko += 64) {
    for (int i = 0; i < 4; ++i) {
      int chunk = i * 256 + tid;
      int r = chunk >> 3; int cb = (chunk & 7) << 4;
      int sb = cb ^ ((r & 7) << 4);
      gl_lds16((const char*)(A + (arow0 + r) * K + ko) + sb, (char*)As + chunk * 16);
      gl_lds16((const char*)(Bm + (brow0 + r) * K + ko) + sb, (char*)Bs + chunk * 16);
    }
    __syncthreads();
    for (int kk = 0; kk < 2; ++kk) {
      const int bofs = kk * 64 + (lane >> 4) * 16;
      short8 af[4], bf[4];
      for (int m = 0; m < 4; ++m) {
        int r = wm * 64 + m * 16 + (lane & 15);
        af[m] = *(const short8*)((const char*)As + r * 128 + (bofs ^ ((r & 7) << 4)));
      }
      for (int n = 0; n < 4; ++n) {
        int r = wn * 64 + n * 16 + (lane & 15);
        bf[n] = *(const short8*)((const char*)Bs + r * 128 + (bofs ^ ((r & 7) << 4)));
      }
      for (int m = 0; m < 4; ++m)
        for (int n = 0; n < 4; ++n)
          acc[m][n] = __builtin_amdgcn_mfma_f32_16x16x32_bf16(af[m], bf[n], acc[m][n], 0, 0, 0);
    }
    __syncthreads();
  }
  for (int n = 0; n < 4; ++n) {
    int col = (int)brow0 + wn * 64 + n * 16 + (lane & 15);
    float bv = bias[col];
    for (int m = 0; m < 4; ++m)
      for (int r2 = 0; r2 < 4; ++r2) {
        size_t row = arow0 + wm * 64 + m * 16 + (lane >> 4) * 4 + r2;
        float v = acc[m][n][r2] + bv;
        if (GX32) ((float*)C)[row * G3 + col] = v;
        else      ((u16*)C)[row * G3 + col] = f2bf(v);
      }
  }
}

// ---------------- persistent GRU recurrence (time-chunked) ------------------
// 128 blocks = 4 batch-groups (64 rows) x 32 hidden-slices (16 units).
// Per block: W_hh slice (48 gate-rows x 512) bf16 in LDS (48KB, XOR-swizzled),
// own h slice carried fp32 in registers (persisted in hstate across chunks),
// published bf16 for the group's MFMA. Flag release/acquire within each
// 32-block group; double-buffered h; flags monotonic across chunk launches.
template<int LAYER, bool GX32>
__global__ __launch_bounds__(256, 1)
void rnn_kernel(const u16* __restrict__ Whh, const float* __restrict__ bhh,
                const void* __restrict__ gx, u16* __restrict__ hpub,
                int* __restrict__ flags, float* __restrict__ hstate,
                u16* __restrict__ hseq, float* __restrict__ hfin,
                int t0, int Tc) {
  __shared__ u16 Wl[48 * 512];
  __shared__ float bl[48];
  const int bid = blockIdx.x;
  const int g = bid & 3;    // batch group (64 rows)
  const int s = bid >> 2;   // hidden slice (16 units), 0..31
  const int tid = threadIdx.x;
  const int lane = tid & 63;
  const int wm = tid >> 6;  // M-tile (16 batch rows), 0..3

  // Load + swizzle W_hh slice: Wl[r][x] = W[grow(r)][x ^ ((r&7)<<4)] (bytes)
  for (int idx = tid; idx < 3072; idx += 256) {
    int r = idx >> 6, c16 = idx & 63;
    int grow = (r >> 4) * 512 + s * 16 + (r & 15);
    int sb = (c16 << 4) ^ ((r & 7) << 4);
    uint4 v = *(const uint4*)((const char*)(Whh + (size_t)grow * 512) + sb);
    *(uint4*)((char*)Wl + r * 1024 + (c16 << 4)) = v;
  }
  if (tid < 48) bl[tid] = bhh[(tid >> 4) * 512 + s * 16 + (tid & 15)];
  __syncthreads();

  const int ul = lane & 15;               // local unit 0..15
  const int gu = s * 16 + ul;             // global unit
  const int q = lane >> 4;                // 0..3
  const int brow0 = g * 64 + wm * 16;
  const float b_r = bl[ul], b_z = bl[16 + ul], b_n = bl[32 + ul];
  const int r_r = ul, r_z = 16 + ul, r_n = 32 + ul;
  const int swz = (ul & 7) << 4;          // same for all three (16,32 = 0 mod 8)

  float h_reg[4];
  if (t0 == 0) {
    for (int r2 = 0; r2 < 4; ++r2) h_reg[r2] = 0.f;
  } else {
    for (int r2 = 0; r2 < 4; ++r2)
      h_reg[r2] = hstate[(size_t)(brow0 + q * 4 + r2) * 512 + gu];
  }

  for (int t = t0; t < t0 + Tc; ++t) {
    // gx prefetch (independent of h -> issued before the flag spin)
    float xr[4], xz[4], xn[4];
    for (int r2 = 0; r2 < 4; ++r2) {
      size_t base = ((size_t)(brow0 + q * 4 + r2) * Tc + (t - t0)) * G3 + gu;
      if (GX32) {
        const float* Gp = (const float*)gx;
        xr[r2] = Gp[base]; xz[r2] = Gp[base + 512]; xn[r2] = Gp[base + 1024];
      } else {
        const u16* Gp = (const u16*)gx;
        xr[r2] = bf2f(Gp[base]); xz[r2] = bf2f(Gp[base + 512]); xn[r2] = bf2f(Gp[base + 1024]);
      }
    }
    float ghr[4], ghz[4], ghn[4];
    if (t == 0) {
      for (int r2 = 0; r2 < 4; ++r2) { ghr[r2] = b_r; ghz[r2] = b_z; ghn[r2] = b_n; }
    } else {
      if (tid < 32) {
        int cap = 0;
        while (__hip_atomic_load(&flags[g * 32 + tid], __ATOMIC_ACQUIRE,
                                 __HIP_MEMORY_SCOPE_AGENT) < t) {
          __builtin_amdgcn_s_sleep(1);
          if (++cap > 300000) break;  // deadlock breaker (never hit normally)
        }
      }
      __syncthreads();
      const u16* hp = hpub + (size_t)(t & 1) * (256 * 512);
      const int arow = g * 64 + wm * 16 + (lane & 15);
      f32x4 ar = {0.f,0.f,0.f,0.f}, az = {0.f,0.f,0.f,0.f}, an = {0.f,0.f,0.f,0.f};
      for (int kk = 0; kk < 16; ++kk) {
        short8 a = *(const short8*)(hp + (size_t)arow * 512 + kk * 32 + q * 8);
        const int bofs = (kk * 64 + q * 16) ^ swz;
        short8 b0 = *(const short8*)((const char*)Wl + r_r * 1024 + bofs);
        short8 b1 = *(const short8*)((const char*)Wl + r_z * 1024 + bofs);
        short8 b2 = *(const short8*)((const char*)Wl + r_n * 1024 + bofs);
        ar = __builtin_amdgcn_mfma_f32_16x16x32_bf16(a, b0, ar, 0, 0, 0);
        az = __builtin_amdgcn_mfma_f32_16x16x32_bf16(a, b1, az, 0, 0, 0);
        an = __builtin_amdgcn_mfma_f32_16x16x32_bf16(a, b2, an, 0, 0, 0);
      }
      for (int r2 = 0; r2 < 4; ++r2) {
        ghr[r2] = ar[r2] + b_r; ghz[r2] = az[r2] + b_z; ghn[r2] = an[r2] + b_n;
      }
    }
    u16* dst = hpub + (size_t)((t + 1) & 1) * (256 * 512);
    for (int r2 = 0; r2 < 4; ++r2) {
      float rr = sigmoidf_(xr[r2] + ghr[r2]);
      float zz = sigmoidf_(xz[r2] + ghz[r2]);
      float nn = tanhf_(xn[r2] + rr * ghn[r2]);
      float hv = (1.0f - zz) * nn + zz * h_reg[r2];
      h_reg[r2] = hv;
      u16 hb = f2bf(hv);
      int row = brow0 + q * 4 + r2;
      dst[(size_t)row * 512 + gu] = hb;
      if (LAYER == 0) hseq[((size_t)row * Tc + (t - t0)) * 512 + gu] = hb;
      else if (t == T_SZ - 1) hfin[(size_t)row * 512 + gu] = hv;
    }
    __threadfence();
    __syncthreads();
    if (tid == 0)
      __hip_atomic_store(&flags[g * 32 + s], t + 1, __ATOMIC_RELEASE,
                         __HIP_MEMORY_SCOPE_AGENT);
  }
  // persist h for next chunk
  for (int r2 = 0; r2 < 4; ++r2)
    hstate[(size_t)(brow0 + q * 4 + r2) * 512 + gu] = h_reg[r2];
}

// ---------------- final FC: out[b] = h1[b,:] . w_fc + b_fc ------------------
__global__ __launch_bounds__(256)
void fc_kernel(const float* __restrict__ h, const float* __restrict__ w,
               const float* __restrict__ bfc, float* __restrict__ out) {
  int b = blockIdx.x; int tid = threadIdx.x;
  float s = h[(size_t)b * 512 + tid] * w[tid] + h[(size_t)b * 512 + tid + 256] * w[tid + 256];
  for (int o = 32; o; o >>= 1) s += __shfl_xor(s, o);
  __shared__ float ws4[4];
  if ((tid & 63) == 0) ws4[tid >> 6] = s;
  __syncthreads();
  if (tid == 0) out[b] = ws4[0] + ws4[1] + ws4[2] + ws4[3] + bfc[0];
}

extern "C" void kernel_launch(void* const* d_in, const int* in_sizes, int n_in,
                              void* d_out, int out_size, void* d_ws, size_t ws_size,
                              hipStream_t stream) {
  const float* x     = (const float*)d_in[0];
  const float* v_ih0 = (const float*)d_in[1];
  const float* g_ih0 = (const float*)d_in[2];
  const float* b_ih0 = (const float*)d_in[3];
  const float* v_hh0 = (const float*)d_in[4];
  const float* g_hh0 = (const float*)d_in[5];
  const float* b_hh0 = (const float*)d_in[6];
  const float* v_ih1 = (const float*)d_in[7];
  const float* g_ih1 = (const float*)d_in[8];
  const float* b_ih1 = (const float*)d_in[9];
  const float* v_hh1 = (const float*)d_in[10];
  const float* g_hh1 = (const float*)d_in[11];
  const float* b_hh1 = (const float*)d_in[12];
  const float* w_fc  = (const float*)d_in[13];
  const float* b_fc  = (const float*)d_in[14];
  float* out = (float*)d_out;

  auto pad = [](size_t b) { return (b + 255) & ~(size_t)255; };
  const size_t b_flags = 1024;                       // 2 layers x 128 ints
  const size_t b_h1f   = (size_t)256 * 512 * 4;
  const size_t b_hpub  = (size_t)2 * 256 * 512 * 2;  // per layer, double-buffered
  const size_t b_hst   = (size_t)256 * 512 * 4;      // per layer
  const size_t b_wih0  = (size_t)G3 * IN_SZ * 2;
  const size_t b_w512  = (size_t)G3 * H_SZ * 2;
  const size_t fixed = pad(b_flags) + pad(b_h1f) + 2 * pad(b_hpub) + 2 * pad(b_hst)
                     + pad(b_wih0) + 3 * pad(b_w512);

  // pick largest time-chunk + gx dtype that fits ws_size
  int Tc = 0; bool gx32 = true;
  {
    const int tcs[5] = {256, 64, 32, 16, 8};
    for (int i = 0; i < 5 && !Tc; ++i) {
      int c = tcs[i];
      size_t need = fixed + pad((size_t)256 * c * 64 * 2)
                  + pad((size_t)256 * c * 512 * 2) + pad((size_t)256 * c * G3 * 4);
      if (need <= ws_size) { Tc = c; gx32 = true; }
    }
    const int tcs2[6] = {256, 64, 32, 16, 8, 4};
    for (int i = 0; i < 6 && !Tc; ++i) {
      int c = tcs2[i];
      size_t need = fixed + pad((size_t)256 * c * 64 * 2)
                  + pad((size_t)256 * c * 512 * 2) + pad((size_t)256 * c * G3 * 2);
      if (need <= ws_size) { Tc = c; gx32 = false; }
    }
    if (!Tc) return;  // workspace unusably small
  }

  char* w = (char*)d_ws;
  size_t off = 0;
  auto alloc = [&](size_t bytes) -> char* {
    char* p = w + off; off += (bytes + 255) & ~(size_t)255; return p;
  };
  int*   flags  = (int*)alloc(b_flags);
  float* h1f    = (float*)alloc(b_h1f);
  u16*   hpub0  = (u16*)alloc(b_hpub);
  u16*   hpub1  = (u16*)alloc(b_hpub);
  float* hst0   = (float*)alloc(b_hst);
  float* hst1   = (float*)alloc(b_hst);
  u16*   wih0   = (u16*)alloc(b_wih0);
  u16*   whh0   = (u16*)alloc(b_w512);
  u16*   wih1   = (u16*)alloc(b_w512);
  u16*   whh1   = (u16*)alloc(b_w512);
  u16*   xbc    = (u16*)alloc((size_t)256 * Tc * 64 * 2);
  u16*   h0c    = (u16*)alloc((size_t)256 * Tc * 512 * 2);
  void*  gx     = (void*)alloc((size_t)256 * Tc * G3 * (gx32 ? 4 : 2));

  hipMemsetAsync(flags, 0, b_flags, stream);
  norm_cast_kernel<<<384, 256, 0, stream>>>(v_ih0, g_ih0, wih0, IN_SZ);
  norm_cast_kernel<<<384, 256, 0, stream>>>(v_hh0, g_hh0, whh0, H_SZ);
  norm_cast_kernel<<<384, 256, 0, stream>>>(v_ih1, g_ih1, wih1, H_SZ);
  norm_cast_kernel<<<384, 256, 0, stream>>>(v_hh1, g_hh1, whh1, H_SZ);

  dim3 ggrid(G3 / 128, 2 * Tc);  // (1536/128, 256*Tc/128)
  for (int t0 = 0; t0 < T_SZ; t0 += Tc) {
    castx_kernel<<<Tc * 16, 256, 0, stream>>>(x, xbc, t0, Tc);
    if (gx32) {
      gemm_kernel<true><<<ggrid, 256, 0, stream>>>(xbc, wih0, b_ih0, gx, IN_SZ);
      rnn_kernel<0, true><<<128, 256, 0, stream>>>(whh0, b_hh0, gx, hpub0, flags,
                                                   hst0, h0c, nullptr, t0, Tc);
      gemm_kernel<true><<<ggrid, 256, 0, stream>>>(h0c, wih1, b_ih1, gx, H_SZ);
      rnn_kernel<1, true><<<128, 256, 0, stream>>>(whh1, b_hh1, gx, hpub1, flags + 128,
                                                   hst1, nullptr, h1f, t0, Tc);
    } else {
      gemm_kernel<false><<<ggrid, 256, 0, stream>>>(xbc, wih0, b_ih0, gx, IN_SZ);
      rnn_kernel<0, false><<<128, 256, 0, stream>>>(whh0, b_hh0, gx, hpub0, flags,
                                                    hst0, h0c, nullptr, t0, Tc);
      gemm_kernel<false><<<ggrid, 256, 0, stream>>>(h0c, wih1, b_ih1, gx, H_SZ);
      rnn_kernel<1, false><<<128, 256, 0, stream>>>(whh1, b_hh1, gx, hpub1, flags + 128,
                                                    hst1, nullptr, h1f, t0, Tc);
    }
  }
  fc_kernel<<<256, 256, 0, stream>>>(h1f, w_fc, b_fc, out);
}

// Round 3
// 9978.722 us; speedup vs baseline: 1.1287x; 1.1287x over previous
//
#include <hip/hip_runtime.h>
#include <hip/hip_bf16.h>
#include <cstdint>
#include <cstddef>

typedef unsigned short u16;
typedef __attribute__((ext_vector_type(4))) float f32x4;
typedef __attribute__((ext_vector_type(8))) short short8;

#define B_SZ 256
#define T_SZ 256
#define IN_SZ 64
#define H_SZ 512
#define G3 1536
#define BH (256 * 512)   // elements per h ring slot

__device__ __forceinline__ float bf2f(u16 u) {
  union { unsigned int i; float f; } v; v.i = ((unsigned int)u) << 16; return v.f;
}
__device__ __forceinline__ u16 f2bf(float f) {
  union { float f; unsigned int i; } v; v.f = f;
  unsigned int x = v.i;
  unsigned int r = (x + 0x7fffu + ((x >> 16) & 1u)) >> 16;  // RNE
  return (u16)r;
}
__device__ __forceinline__ float sigmoidf_(float x) { return 1.0f / (1.0f + __expf(-x)); }
__device__ __forceinline__ float tanhf_(float x) {
  float e = __expf(-2.0f * x); return (1.0f - e) / (1.0f + e);
}
// relaxed spin + one acquire on exit (avoids per-poll invalidate storms)
__device__ __forceinline__ void spin_ge(int* p, int v) {
  int cap = 0;
  while (__hip_atomic_load(p, __ATOMIC_RELAXED, __HIP_MEMORY_SCOPE_AGENT) < v) {
    __builtin_amdgcn_s_sleep(1);
    if (++cap > 300000) return;  // hang breaker; never hit in normal runs
  }
  (void)__hip_atomic_load(p, __ATOMIC_ACQUIRE, __HIP_MEMORY_SCOPE_AGENT);
}
__device__ __forceinline__ void spin_ge_relaxed(int* p, int v) {
  int cap = 0;
  while (__hip_atomic_load(p, __ATOMIC_RELAXED, __HIP_MEMORY_SCOPE_AGENT) < v) {
    __builtin_amdgcn_s_sleep(1);
    if (++cap > 300000) return;
  }
}

// ---------------- weight-norm + bf16 cast: one wave per row ----------------
__global__ __launch_bounds__(256)
void norm_cast_kernel(const float* __restrict__ v, const float* __restrict__ g,
                      u16* __restrict__ out, int cols) {
  int row = blockIdx.x * 4 + (threadIdx.x >> 6);
  int lane = threadIdx.x & 63;
  const float* vr = v + (size_t)row * cols;
  float s = 0.f;
  for (int c = lane; c < cols; c += 64) { float t = vr[c]; s += t * t; }
  for (int o = 32; o; o >>= 1) s += __shfl_xor(s, o);
  float scale = g[row] / sqrtf(s);
  for (int c = lane; c < cols; c += 64) out[(size_t)row * cols + c] = f2bf(vr[c] * scale);
}

// full elementwise fp32->bf16 cast of x ([B][T][64] layout preserved)
__global__ __launch_bounds__(256)
void castx_kernel(const float* __restrict__ x, u16* __restrict__ xb) {
  int i = blockIdx.x * 256 + threadIdx.x;
  float4 v = ((const float4*)x)[i];
  ushort4 o;
  o.x = f2bf(v.x); o.y = f2bf(v.y); o.z = f2bf(v.z); o.w = f2bf(v.w);
  ((ushort4*)xb)[i] = o;
}

// ---------------- fused 2-layer persistent GRU pipeline ---------------------
// 128 blocks, 512 threads. bid<64: layer-0 role; bid>=64: layer-1 role.
// Within role: g = batch group (64 rows), s = hidden slice (32 units).
// L0: gx0 on-the-fly (Wih0 12KB LDS) + gh0 (Whh0 96KB LDS, XOR-swizzled),
//     publishes h0 into 4-slot ring; WAR-guarded by L1 progress (h1flag>=t-3).
// L1: lags 1 step; gx1 on-the-fly with Wih1 B-frags streamed from L2 +
//     gh1 (Whh1 96KB LDS); h1 double-buffered ring.
// Max intra-layer skew = 1 step (all-to-all each step), so rings are safe.
__global__ __launch_bounds__(512, 1)
void fused_rnn_kernel(const u16* __restrict__ whh0, const u16* __restrict__ wih0,
                      const float* __restrict__ bih0p, const float* __restrict__ bhh0p,
                      const u16* __restrict__ whh1, const u16* __restrict__ wih1,
                      const float* __restrict__ bih1p, const float* __restrict__ bhh1p,
                      const u16* __restrict__ xb, u16* __restrict__ h0ring,
                      u16* __restrict__ h1ring, float* __restrict__ h1fin,
                      int* __restrict__ h0flag, int* __restrict__ h1flag) {
  __shared__ u16 Wl[96 * 512];   // Whh slice, swizzled
  __shared__ u16 Wx[96 * 64];    // Wih0 slice (L0 only), swizzled
  __shared__ float bih[96], bhh[96];

  const int L = blockIdx.x >> 6;
  const int r6 = blockIdx.x & 63;
  const int g = r6 & 3;    // batch group
  const int s = r6 >> 2;   // hidden slice (32 units), 0..15
  const int tid = threadIdx.x;
  const int lane = tid & 63;
  const int wv = tid >> 6;
  const int wm = wv >> 1;          // m-tile 0..3 (16 rows)
  const int wk = wv & 1;           // unit half
  const int q = lane >> 4;
  const int ul = wk * 16 + (lane & 15);   // local unit 0..31
  const int gu = s * 32 + ul;
  const int arow = g * 64 + wm * 16 + (lane & 15);
  const int swz = (ul & 7) << 4;

  const u16* whhp = L ? whh1 : whh0;
  // stage Whh slice (96 rows x 1024B), pre-swizzled source -> linear LDS
  for (int idx = tid; idx < 6144; idx += 512) {
    int r = idx >> 6, c16 = idx & 63;
    int grow = (r >> 5) * 512 + s * 32 + (r & 31);
    int sb = (c16 << 4) ^ ((r & 7) << 4);
    uint4 v = *(const uint4*)((const char*)whhp + (size_t)grow * 1024 + sb);
    *(uint4*)((char*)Wl + r * 1024 + (c16 << 4)) = v;
  }
  if (L == 0) {
    // stage Wih0 slice (96 rows x 128B)
    for (int idx = tid; idx < 768; idx += 512) {
      int r = idx >> 3, c16 = idx & 7;
      int grow = (r >> 5) * 512 + s * 32 + (r & 31);
      int sb = (c16 << 4) ^ ((r & 7) << 4);
      uint4 v = *(const uint4*)((const char*)wih0 + (size_t)grow * 128 + sb);
      *(uint4*)((char*)Wx + r * 128 + (c16 << 4)) = v;
    }
  }
  if (tid < 96) {
    const float* bi = L ? bih1p : bih0p;
    const float* bh = L ? bhh1p : bhh0p;
    int gr = (tid >> 5) * 512 + s * 32 + (tid & 31);
    bih[tid] = bi[gr]; bhh[tid] = bh[gr];
  }
  __syncthreads();

  const float bi_r = bih[ul], bi_z = bih[32 + ul], bi_n = bih[64 + ul];
  const float bh_r = bhh[ul], bh_z = bhh[32 + ul], bh_n = bhh[64 + ul];
  float h_reg[4] = {0.f, 0.f, 0.f, 0.f};

  if (L == 0) {
    for (int t = 0; t < T_SZ; ++t) {
      // xb A-frags (independent of flags -> issued before spins)
      const u16* xp = xb + ((size_t)arow * T_SZ + t) * 64;
      short8 ax0 = *(const short8*)(xp + q * 8);
      short8 ax1 = *(const short8*)(xp + 32 + q * 8);
      if (t > 0 && tid < 16) spin_ge(&h0flag[g * 16 + tid], t);
      if (t >= 4 && tid >= 16 && tid < 32)
        spin_ge_relaxed(&h1flag[g * 16 + (tid - 16)], t - 3);   // WAR guard
      __syncthreads();
      f32x4 accr = {0.f,0.f,0.f,0.f}, accz = {0.f,0.f,0.f,0.f};
      f32x4 axn  = {0.f,0.f,0.f,0.f}, ahn  = {0.f,0.f,0.f,0.f};
      // gx0: K=64 from LDS Wih0 slice
      {
        int b0 = (q * 16) ^ swz, b1 = (64 + q * 16) ^ swz;
        short8 wr0 = *(const short8*)((const char*)Wx + (size_t)ul * 128 + b0);
        short8 wz0 = *(const short8*)((const char*)Wx + (size_t)(32 + ul) * 128 + b0);
        short8 wn0 = *(const short8*)((const char*)Wx + (size_t)(64 + ul) * 128 + b0);
        short8 wr1 = *(const short8*)((const char*)Wx + (size_t)ul * 128 + b1);
        short8 wz1 = *(const short8*)((const char*)Wx + (size_t)(32 + ul) * 128 + b1);
        short8 wn1 = *(const short8*)((const char*)Wx + (size_t)(64 + ul) * 128 + b1);
        accr = __builtin_amdgcn_mfma_f32_16x16x32_bf16(ax0, wr0, accr, 0, 0, 0);
        accz = __builtin_amdgcn_mfma_f32_16x16x32_bf16(ax0, wz0, accz, 0, 0, 0);
        axn  = __builtin_amdgcn_mfma_f32_16x16x32_bf16(ax0, wn0, axn, 0, 0, 0);
        accr = __builtin_amdgcn_mfma_f32_16x16x32_bf16(ax1, wr1, accr, 0, 0, 0);
        accz = __builtin_amdgcn_mfma_f32_16x16x32_bf16(ax1, wz1, accz, 0, 0, 0);
        axn  = __builtin_amdgcn_mfma_f32_16x16x32_bf16(ax1, wn1, axn, 0, 0, 0);
      }
      if (t > 0) {
        const u16* hp = h0ring + (size_t)((t - 1) & 3) * BH;
        #pragma unroll 4
        for (int kk = 0; kk < 16; ++kk) {
          short8 a = *(const short8*)(hp + (size_t)arow * 512 + kk * 32 + q * 8);
          int bofs = (kk * 64 + q * 16) ^ swz;
          short8 b0 = *(const short8*)((const char*)Wl + (size_t)ul * 1024 + bofs);
          short8 b1 = *(const short8*)((const char*)Wl + (size_t)(32 + ul) * 1024 + bofs);
          short8 b2 = *(const short8*)((const char*)Wl + (size_t)(64 + ul) * 1024 + bofs);
          accr = __builtin_amdgcn_mfma_f32_16x16x32_bf16(a, b0, accr, 0, 0, 0);
          accz = __builtin_amdgcn_mfma_f32_16x16x32_bf16(a, b1, accz, 0, 0, 0);
          ahn  = __builtin_amdgcn_mfma_f32_16x16x32_bf16(a, b2, ahn, 0, 0, 0);
        }
      }
      u16* dst = h0ring + (size_t)(t & 3) * BH;
      for (int r2 = 0; r2 < 4; ++r2) {
        float rr = sigmoidf_(accr[r2] + bi_r + bh_r);
        float zz = sigmoidf_(accz[r2] + bi_z + bh_z);
        float nn = tanhf_(axn[r2] + bi_n + rr * (ahn[r2] + bh_n));
        float hv = (1.0f - zz) * nn + zz * h_reg[r2];
        h_reg[r2] = hv;
        dst[(size_t)(g * 64 + wm * 16 + q * 4 + r2) * 512 + gu] = f2bf(hv);
      }
      __threadfence();
      __syncthreads();
      if (tid == 0)
        __hip_atomic_store(&h0flag[g * 16 + s], t + 1, __ATOMIC_RELEASE,
                           __HIP_MEMORY_SCOPE_AGENT);
    }
  } else {
    const u16* wr = wih1 + (size_t)(s * 32 + ul) * 512;
    const u16* wz = wih1 + (size_t)(512 + s * 32 + ul) * 512;
    const u16* wn = wih1 + (size_t)(1024 + s * 32 + ul) * 512;
    for (int t = 0; t < T_SZ; ++t) {
      if (tid < 16) spin_ge(&h0flag[g * 16 + tid], t + 1);
      if (t > 0 && tid >= 16 && tid < 32) spin_ge(&h1flag[g * 16 + (tid - 16)], t);
      __syncthreads();
      f32x4 accr = {0.f,0.f,0.f,0.f}, accz = {0.f,0.f,0.f,0.f};
      f32x4 axn  = {0.f,0.f,0.f,0.f}, ahn  = {0.f,0.f,0.f,0.f};
      // gx1: K=512 from h0(t), Wih1 B-frags streamed from global (L2-resident)
      {
        const u16* hp0 = h0ring + (size_t)(t & 3) * BH;
        #pragma unroll 4
        for (int kk = 0; kk < 16; ++kk) {
          short8 a0 = *(const short8*)(hp0 + (size_t)arow * 512 + kk * 32 + q * 8);
          short8 br = *(const short8*)(wr + kk * 32 + q * 8);
          short8 bz = *(const short8*)(wz + kk * 32 + q * 8);
          short8 bn = *(const short8*)(wn + kk * 32 + q * 8);
          accr = __builtin_amdgcn_mfma_f32_16x16x32_bf16(a0, br, accr, 0, 0, 0);
          accz = __builtin_amdgcn_mfma_f32_16x16x32_bf16(a0, bz, accz, 0, 0, 0);
          axn  = __builtin_amdgcn_mfma_f32_16x16x32_bf16(a0, bn, axn, 0, 0, 0);
        }
      }
      if (t > 0) {
        const u16* hp1 = h1ring + (size_t)((t - 1) & 1) * BH;
        #pragma unroll 4
        for (int kk = 0; kk < 16; ++kk) {
          short8 a1 = *(const short8*)(hp1 + (size_t)arow * 512 + kk * 32 + q * 8);
          int bofs = (kk * 64 + q * 16) ^ swz;
          short8 b0 = *(const short8*)((const char*)Wl + (size_t)ul * 1024 + bofs);
          short8 b1 = *(const short8*)((const char*)Wl + (size_t)(32 + ul) * 1024 + bofs);
          short8 b2 = *(const short8*)((const char*)Wl + (size_t)(64 + ul) * 1024 + bofs);
          accr = __builtin_amdgcn_mfma_f32_16x16x32_bf16(a1, b0, accr, 0, 0, 0);
          accz = __builtin_amdgcn_mfma_f32_16x16x32_bf16(a1, b1, accz, 0, 0, 0);
          ahn  = __builtin_amdgcn_mfma_f32_16x16x32_bf16(a1, b2, ahn, 0, 0, 0);
        }
      }
      u16* dst = h1ring + (size_t)(t & 1) * BH;
      for (int r2 = 0; r2 < 4; ++r2) {
        float rr = sigmoidf_(accr[r2] + bi_r + bh_r);
        float zz = sigmoidf_(accz[r2] + bi_z + bh_z);
        float nn = tanhf_(axn[r2] + bi_n + rr * (ahn[r2] + bh_n));
        float hv = (1.0f - zz) * nn + zz * h_reg[r2];
        h_reg[r2] = hv;
        int row = g * 64 + wm * 16 + q * 4 + r2;
        dst[(size_t)row * 512 + gu] = f2bf(hv);
        if (t == T_SZ - 1) h1fin[(size_t)row * 512 + gu] = hv;
      }
      __threadfence();
      __syncthreads();
      if (tid == 0)
        __hip_atomic_store(&h1flag[g * 16 + s], t + 1, __ATOMIC_RELEASE,
                           __HIP_MEMORY_SCOPE_AGENT);
    }
  }
}

// ---------------- final FC: out[b] = h1[b,:] . w_fc + b_fc ------------------
__global__ __launch_bounds__(256)
void fc_kernel(const float* __restrict__ h, const float* __restrict__ w,
               const float* __restrict__ bfc, float* __restrict__ out) {
  int b = blockIdx.x; int tid = threadIdx.x;
  float s = h[(size_t)b * 512 + tid] * w[tid] + h[(size_t)b * 512 + tid + 256] * w[tid + 256];
  for (int o = 32; o; o >>= 1) s += __shfl_xor(s, o);
  __shared__ float ws4[4];
  if ((tid & 63) == 0) ws4[tid >> 6] = s;
  __syncthreads();
  if (tid == 0) out[b] = ws4[0] + ws4[1] + ws4[2] + ws4[3] + bfc[0];
}

extern "C" void kernel_launch(void* const* d_in, const int* in_sizes, int n_in,
                              void* d_out, int out_size, void* d_ws, size_t ws_size,
                              hipStream_t stream) {
  const float* x     = (const float*)d_in[0];
  const float* v_ih0 = (const float*)d_in[1];
  const float* g_ih0 = (const float*)d_in[2];
  const float* b_ih0 = (const float*)d_in[3];
  const float* v_hh0 = (const float*)d_in[4];
  const float* g_hh0 = (const float*)d_in[5];
  const float* b_hh0 = (const float*)d_in[6];
  const float* v_ih1 = (const float*)d_in[7];
  const float* g_ih1 = (const float*)d_in[8];
  const float* b_ih1 = (const float*)d_in[9];
  const float* v_hh1 = (const float*)d_in[10];
  const float* g_hh1 = (const float*)d_in[11];
  const float* b_hh1 = (const float*)d_in[12];
  const float* w_fc  = (const float*)d_in[13];
  const float* b_fc  = (const float*)d_in[14];
  float* out = (float*)d_out;

  char* w = (char*)d_ws;
  size_t off = 0;
  auto alloc = [&](size_t bytes) -> char* {
    char* p = w + off; off += (bytes + 255) & ~(size_t)255; return p;
  };
  int*   flags  = (int*)alloc(1024);                      // h0flag[64] + h1flag[64]
  float* h1fin  = (float*)alloc((size_t)256 * 512 * 4);
  u16*   h0ring = (u16*)alloc((size_t)4 * BH * 2);
  u16*   h1ring = (u16*)alloc((size_t)2 * BH * 2);
  u16*   xb     = (u16*)alloc((size_t)B_SZ * T_SZ * IN_SZ * 2);
  u16*   wih0   = (u16*)alloc((size_t)G3 * IN_SZ * 2);
  u16*   whh0   = (u16*)alloc((size_t)G3 * H_SZ * 2);
  u16*   wih1   = (u16*)alloc((size_t)G3 * H_SZ * 2);
  u16*   whh1   = (u16*)alloc((size_t)G3 * H_SZ * 2);
  if (off > ws_size) return;  // needs ~15MB; evidenced ws >= 120MB

  hipMemsetAsync(flags, 0, 1024, stream);
  norm_cast_kernel<<<384, 256, 0, stream>>>(v_ih0, g_ih0, wih0, IN_SZ);
  norm_cast_kernel<<<384, 256, 0, stream>>>(v_hh0, g_hh0, whh0, H_SZ);
  norm_cast_kernel<<<384, 256, 0, stream>>>(v_ih1, g_ih1, wih1, H_SZ);
  norm_cast_kernel<<<384, 256, 0, stream>>>(v_hh1, g_hh1, whh1, H_SZ);
  castx_kernel<<<4096, 256, 0, stream>>>(x, xb);

  fused_rnn_kernel<<<128, 512, 0, stream>>>(whh0, wih0, b_ih0, b_hh0,
                                            whh1, wih1, b_ih1, b_hh1,
                                            xb, h0ring, h1ring, h1fin,
                                            flags, flags + 64);
  fc_kernel<<<256, 256, 0, stream>>>(h1fin, w_fc, b_fc, out);
}

// Round 4
// 2168.211 us; speedup vs baseline: 5.1948x; 4.6023x over previous
//
#include <hip/hip_runtime.h>
#include <hip/hip_bf16.h>
#include <cstdint>
#include <cstddef>

typedef unsigned short u16;
typedef __attribute__((ext_vector_type(4))) float f32x4;
typedef __attribute__((ext_vector_type(8))) short short8;

#define B_SZ 256
#define T_SZ 256
#define IN_SZ 64
#define H_SZ 512
#define G3 1536
#define BH (256 * 512)   // elements per full-batch h ring slot

__device__ __forceinline__ u16 f2bf(float f) {
  union { float f; unsigned int i; } v; v.f = f;
  unsigned int x = v.i;
  unsigned int r = (x + 0x7fffu + ((x >> 16) & 1u)) >> 16;  // RNE
  return (u16)r;
}
__device__ __forceinline__ float sigmoidf_(float x) { return 1.0f / (1.0f + __expf(-x)); }
__device__ __forceinline__ float tanhf_(float x) {
  float e = __expf(-2.0f * x); return (1.0f - e) / (1.0f + e);
}
// relaxed spin: flag lives in THIS XCD's L2 (producer is same-XCD) -> cheap.
__device__ __forceinline__ void spin_rlx(int* p, int v) {
  int cap = 0;
  while (__hip_atomic_load(p, __ATOMIC_RELAXED, __HIP_MEMORY_SCOPE_AGENT) < v) {
    __builtin_amdgcn_s_sleep(1);
    if (++cap > 400000) return;  // hang breaker; never hit in normal runs
  }
}

// ---------------- weight-norm + bf16 cast: one wave per row ----------------
__global__ __launch_bounds__(256)
void norm_cast_kernel(const float* __restrict__ v, const float* __restrict__ g,
                      u16* __restrict__ out, int cols) {
  int row = blockIdx.x * 4 + (threadIdx.x >> 6);
  int lane = threadIdx.x & 63;
  const float* vr = v + (size_t)row * cols;
  float s = 0.f;
  for (int c = lane; c < cols; c += 64) { float t = vr[c]; s += t * t; }
  for (int o = 32; o; o >>= 1) s += __shfl_xor(s, o);
  float scale = g[row] / sqrtf(s);
  for (int c = lane; c < cols; c += 64) out[(size_t)row * cols + c] = f2bf(vr[c] * scale);
}

__global__ __launch_bounds__(256)
void castx_kernel(const float* __restrict__ x, u16* __restrict__ xb) {
  int i = blockIdx.x * 256 + threadIdx.x;
  float4 v = ((const float4*)x)[i];
  ushort4 o;
  o.x = f2bf(v.x); o.y = f2bf(v.y); o.z = f2bf(v.z); o.w = f2bf(v.w);
  ((ushort4*)xb)[i] = o;
}

// ---------------- fused 2-layer persistent GRU, XCD-local sync --------------
// 256 blocks, 256 threads, 1 block/CU (LDS ~157KB). Each block claims a role
// on ITS OWN XCD: group g = xcd (8 groups x 32 batch rows), role r in [0,32):
// r<16 -> L0 slice r; r>=16 -> L1 slice r-16. All 32 communicating blocks
// share one XCD L2 -> sync via relaxed sc0 flag atomics + L1-only invalidate;
// NO agent fences, NO L2 writeback/invalidate in the loop.
__global__ __launch_bounds__(256, 1)
void fused_rnn_kernel(const u16* __restrict__ whh0, const u16* __restrict__ wih0,
                      const float* __restrict__ bih0p, const float* __restrict__ bhh0p,
                      const u16* __restrict__ whh1, const u16* __restrict__ wih1,
                      const float* __restrict__ bih1p, const float* __restrict__ bhh1p,
                      const u16* __restrict__ xb, u16* __restrict__ h0ring,
                      u16* __restrict__ h1ring, float* __restrict__ h1fin,
                      int* __restrict__ flags, int* __restrict__ claim) {
  __shared__ u16 Wl[96 * 512];    // Whh slice (both roles), swizzled, 96KB
  __shared__ u16 Wx[96 * 64];     // L0: Wih0 slice, 12KB
  __shared__ u16 Wx1[96 * 256];   // L1: Wih1 slice K=0..255, 48KB
  __shared__ float bih[96], bhh[96];
  __shared__ int role_sh;

  const int tid = threadIdx.x;
  if (tid == 0) {
    int xcd;
    asm volatile("s_getreg_b32 %0, hwreg(HW_REG_XCC_ID)" : "=s"(xcd));
    xcd &= 7;
    int r = atomicAdd(&claim[xcd], 1);          // device-scope, coherent
    role_sh = xcd * 64 + r;
  }
  __syncthreads();
  const int g = role_sh >> 6;        // batch group == XCD
  const int r = role_sh & 63;
  if (r >= 32) return;               // can't happen (pigeonhole 32/XCD)
  const int L = r >> 4;
  const int s = r & 15;              // hidden slice (32 units)

  const int lane = tid & 63;
  const int wv = tid >> 6;           // 4 waves
  const int wm = wv >> 1;            // 16-row tile 0..1
  const int wk = wv & 1;             // 16-unit half 0..1
  const int q = lane >> 4;
  const int ul = wk * 16 + (lane & 15);   // local unit 0..31
  const int gu = s * 32 + ul;
  const int arow = g * 32 + wm * 16 + (lane & 15);
  const int swz = (ul & 7) << 4;

  // stage Whh slice (96 gate-rows x 1024B), pre-swizzled src -> linear LDS
  const u16* whhp = L ? whh1 : whh0;
  for (int idx = tid; idx < 6144; idx += 256) {
    int rr = idx >> 6, c16 = idx & 63;
    int grow = (rr >> 5) * 512 + s * 32 + (rr & 31);
    int sb = (c16 << 4) ^ ((rr & 7) << 4);
    uint4 vv = *(const uint4*)((const char*)whhp + (size_t)grow * 1024 + sb);
    *(uint4*)((char*)Wl + rr * 1024 + (c16 << 4)) = vv;
  }
  if (L == 0) {
    for (int idx = tid; idx < 768; idx += 256) {   // Wih0 [96][128B]
      int rr = idx >> 3, c16 = idx & 7;
      int grow = (rr >> 5) * 512 + s * 32 + (rr & 31);
      int sb = (c16 << 4) ^ ((rr & 7) << 4);
      uint4 vv = *(const uint4*)((const char*)wih0 + (size_t)grow * 128 + sb);
      *(uint4*)((char*)Wx + rr * 128 + (c16 << 4)) = vv;
    }
  } else {
    for (int idx = tid; idx < 3072; idx += 256) {  // Wih1[:,0:256] [96][512B]
      int rr = idx >> 5, c16 = idx & 31;
      int grow = (rr >> 5) * 512 + s * 32 + (rr & 31);
      int sb = (c16 << 4) ^ ((rr & 7) << 4);
      uint4 vv = *(const uint4*)((const char*)wih1 + (size_t)grow * 1024 + sb);
      *(uint4*)((char*)Wx1 + rr * 512 + (c16 << 4)) = vv;
    }
  }
  if (tid < 96) {
    const float* bi = L ? bih1p : bih0p;
    const float* bh = L ? bhh1p : bhh0p;
    int gr = (tid >> 5) * 512 + s * 32 + (tid & 31);
    bih[tid] = bi[gr]; bhh[tid] = bh[gr];
  }
  __syncthreads();

  const float bi_r = bih[ul], bi_z = bih[32 + ul], bi_n = bih[64 + ul];
  const float bh_r = bhh[ul], bh_z = bhh[32 + ul], bh_n = bhh[64 + ul];
  int* h0f = flags + g * 128;
  int* h1f = h0f + 16;
  float h_reg[4] = {0.f, 0.f, 0.f, 0.f};

  if (L == 0) {
    for (int t = 0; t < T_SZ; ++t) {
      const u16* xp = xb + ((size_t)arow * T_SZ + t) * 64;
      short8 ax0 = *(const short8*)(xp + q * 8);
      short8 ax1 = *(const short8*)(xp + 32 + q * 8);
      if (t > 0 && tid < 16) spin_rlx(&h0f[tid], t);           // peers' h0(t-1)
      if (t >= 8 && tid >= 16 && tid < 32) spin_rlx(&h1f[tid - 16], t - 7); // WAR slot t&7
      __syncthreads();
      asm volatile("buffer_inv sc0" ::: "memory");   // L1-only invalidate
      f32x4 accr = {0.f,0.f,0.f,0.f}, accz = {0.f,0.f,0.f,0.f};
      f32x4 axn  = {0.f,0.f,0.f,0.f}, ahn  = {0.f,0.f,0.f,0.f};
      {  // gx0: K=64 from LDS Wih0
        int b0 = (q * 16) ^ swz, b1 = (64 + q * 16) ^ swz;
        short8 wr0 = *(const short8*)((const char*)Wx + (size_t)ul * 128 + b0);
        short8 wz0 = *(const short8*)((const char*)Wx + (size_t)(32 + ul) * 128 + b0);
        short8 wn0 = *(const short8*)((const char*)Wx + (size_t)(64 + ul) * 128 + b0);
        short8 wr1 = *(const short8*)((const char*)Wx + (size_t)ul * 128 + b1);
        short8 wz1 = *(const short8*)((const char*)Wx + (size_t)(32 + ul) * 128 + b1);
        short8 wn1 = *(const short8*)((const char*)Wx + (size_t)(64 + ul) * 128 + b1);
        accr = __builtin_amdgcn_mfma_f32_16x16x32_bf16(ax0, wr0, accr, 0, 0, 0);
        accz = __builtin_amdgcn_mfma_f32_16x16x32_bf16(ax0, wz0, accz, 0, 0, 0);
        axn  = __builtin_amdgcn_mfma_f32_16x16x32_bf16(ax0, wn0, axn, 0, 0, 0);
        accr = __builtin_amdgcn_mfma_f32_16x16x32_bf16(ax1, wr1, accr, 0, 0, 0);
        accz = __builtin_amdgcn_mfma_f32_16x16x32_bf16(ax1, wz1, accz, 0, 0, 0);
        axn  = __builtin_amdgcn_mfma_f32_16x16x32_bf16(ax1, wn1, axn, 0, 0, 0);
      }
      if (t > 0) {
        const u16* hp = h0ring + (size_t)((t - 1) & 7) * BH;
        #pragma unroll 4
        for (int kk = 0; kk < 16; ++kk) {
          short8 a = *(const short8*)(hp + (size_t)arow * 512 + kk * 32 + q * 8);
          int bofs = (kk * 64 + q * 16) ^ swz;
          short8 b0 = *(const short8*)((const char*)Wl + (size_t)ul * 1024 + bofs);
          short8 b1 = *(const short8*)((const char*)Wl + (size_t)(32 + ul) * 1024 + bofs);
          short8 b2 = *(const short8*)((const char*)Wl + (size_t)(64 + ul) * 1024 + bofs);
          accr = __builtin_amdgcn_mfma_f32_16x16x32_bf16(a, b0, accr, 0, 0, 0);
          accz = __builtin_amdgcn_mfma_f32_16x16x32_bf16(a, b1, accz, 0, 0, 0);
          ahn  = __builtin_amdgcn_mfma_f32_16x16x32_bf16(a, b2, ahn, 0, 0, 0);
        }
      }
      u16* dst = h0ring + (size_t)(t & 7) * BH;
      for (int r2 = 0; r2 < 4; ++r2) {
        float rr = sigmoidf_(accr[r2] + bi_r + bh_r);
        float zz = sigmoidf_(accz[r2] + bi_z + bh_z);
        float nn = tanhf_(axn[r2] + bi_n + rr * (ahn[r2] + bh_n));
        float hv = (1.0f - zz) * nn + zz * h_reg[r2];
        h_reg[r2] = hv;
        dst[(size_t)(g * 32 + wm * 16 + q * 4 + r2) * 512 + gu] = f2bf(hv);
      }
      __syncthreads();  // drains vmcnt(0): stores are in XCD L2 (L1 write-through)
      if (tid == 0)
        __hip_atomic_store(&h0f[s], t + 1, __ATOMIC_RELAXED, __HIP_MEMORY_SCOPE_AGENT);
    }
  } else {
    const u16* wrG = wih1 + (size_t)(s * 32 + ul) * 512 + 256;
    const u16* wzG = wih1 + (size_t)(512 + s * 32 + ul) * 512 + 256;
    const u16* wnG = wih1 + (size_t)(1024 + s * 32 + ul) * 512 + 256;
    for (int t = 0; t < T_SZ; ++t) {
      if (tid < 16) spin_rlx(&h0f[tid], t + 1);                 // h0(t) ready
      if (t > 0 && tid >= 16 && tid < 32) spin_rlx(&h1f[tid - 16], t);  // peers' h1(t-1)
      __syncthreads();
      asm volatile("buffer_inv sc0" ::: "memory");
      f32x4 accr = {0.f,0.f,0.f,0.f}, accz = {0.f,0.f,0.f,0.f};
      f32x4 axn  = {0.f,0.f,0.f,0.f}, ahn  = {0.f,0.f,0.f,0.f};
      const u16* hp0 = h0ring + (size_t)(t & 7) * BH;
      #pragma unroll 4
      for (int kk = 0; kk < 8; ++kk) {      // gx1 K=0..255 (Wih1 in LDS)
        short8 a0 = *(const short8*)(hp0 + (size_t)arow * 512 + kk * 32 + q * 8);
        int bofs = (kk * 64 + q * 16) ^ swz;
        short8 br = *(const short8*)((const char*)Wx1 + (size_t)ul * 512 + bofs);
        short8 bz = *(const short8*)((const char*)Wx1 + (size_t)(32 + ul) * 512 + bofs);
        short8 bn = *(const short8*)((const char*)Wx1 + (size_t)(64 + ul) * 512 + bofs);
        accr = __builtin_amdgcn_mfma_f32_16x16x32_bf16(a0, br, accr, 0, 0, 0);
        accz = __builtin_amdgcn_mfma_f32_16x16x32_bf16(a0, bz, accz, 0, 0, 0);
        axn  = __builtin_amdgcn_mfma_f32_16x16x32_bf16(a0, bn, axn, 0, 0, 0);
      }
      #pragma unroll 4
      for (int kk = 0; kk < 8; ++kk) {      // gx1 K=256..511 (streamed, L2-resident)
        short8 a0 = *(const short8*)(hp0 + (size_t)arow * 512 + 256 + kk * 32 + q * 8);
        short8 br = *(const short8*)(wrG + kk * 32 + q * 8);
        short8 bz = *(const short8*)(wzG + kk * 32 + q * 8);
        short8 bn = *(const short8*)(wnG + kk * 32 + q * 8);
        accr = __builtin_amdgcn_mfma_f32_16x16x32_bf16(a0, br, accr, 0, 0, 0);
        accz = __builtin_amdgcn_mfma_f32_16x16x32_bf16(a0, bz, accz, 0, 0, 0);
        axn  = __builtin_amdgcn_mfma_f32_16x16x32_bf16(a0, bn, axn, 0, 0, 0);
      }
      if (t > 0) {
        const u16* hp1 = h1ring + (size_t)((t - 1) & 3) * BH;
        #pragma unroll 4
        for (int kk = 0; kk < 16; ++kk) {   // gh1 K=512 (Whh1 in LDS)
          short8 a1 = *(const short8*)(hp1 + (size_t)arow * 512 + kk * 32 + q * 8);
          int bofs = (kk * 64 + q * 16) ^ swz;
          short8 b0 = *(const short8*)((const char*)Wl + (size_t)ul * 1024 + bofs);
          short8 b1 = *(const short8*)((const char*)Wl + (size_t)(32 + ul) * 1024 + bofs);
          short8 b2 = *(const short8*)((const char*)Wl + (size_t)(64 + ul) * 1024 + bofs);
          accr = __builtin_amdgcn_mfma_f32_16x16x32_bf16(a1, b0, accr, 0, 0, 0);
          accz = __builtin_amdgcn_mfma_f32_16x16x32_bf16(a1, b1, accz, 0, 0, 0);
          ahn  = __builtin_amdgcn_mfma_f32_16x16x32_bf16(a1, b2, ahn, 0, 0, 0);
        }
      }
      u16* dst = h1ring + (size_t)(t & 3) * BH;
      for (int r2 = 0; r2 < 4; ++r2) {
        float rr = sigmoidf_(accr[r2] + bi_r + bh_r);
        float zz = sigmoidf_(accz[r2] + bi_z + bh_z);
        float nn = tanhf_(axn[r2] + bi_n + rr * (ahn[r2] + bh_n));
        float hv = (1.0f - zz) * nn + zz * h_reg[r2];
        h_reg[r2] = hv;
        int row = g * 32 + wm * 16 + q * 4 + r2;
        dst[(size_t)row * 512 + gu] = f2bf(hv);
        if (t == T_SZ - 1) h1fin[(size_t)row * 512 + gu] = hv;
      }
      __syncthreads();
      if (tid == 0)
        __hip_atomic_store(&h1f[s], t + 1, __ATOMIC_RELAXED, __HIP_MEMORY_SCOPE_AGENT);
    }
  }
}

// ---------------- final FC: out[b] = h1[b,:] . w_fc + b_fc ------------------
__global__ __launch_bounds__(256)
void fc_kernel(const float* __restrict__ h, const float* __restrict__ w,
               const float* __restrict__ bfc, float* __restrict__ out) {
  int b = blockIdx.x; int tid = threadIdx.x;
  float s = h[(size_t)b * 512 + tid] * w[tid] + h[(size_t)b * 512 + tid + 256] * w[tid + 256];
  for (int o = 32; o; o >>= 1) s += __shfl_xor(s, o);
  __shared__ float ws4[4];
  if ((tid & 63) == 0) ws4[tid >> 6] = s;
  __syncthreads();
  if (tid == 0) out[b] = ws4[0] + ws4[1] + ws4[2] + ws4[3] + bfc[0];
}

extern "C" void kernel_launch(void* const* d_in, const int* in_sizes, int n_in,
                              void* d_out, int out_size, void* d_ws, size_t ws_size,
                              hipStream_t stream) {
  const float* x     = (const float*)d_in[0];
  const float* v_ih0 = (const float*)d_in[1];
  const float* g_ih0 = (const float*)d_in[2];
  const float* b_ih0 = (const float*)d_in[3];
  const float* v_hh0 = (const float*)d_in[4];
  const float* g_hh0 = (const float*)d_in[5];
  const float* b_hh0 = (const float*)d_in[6];
  const float* v_ih1 = (const float*)d_in[7];
  const float* g_ih1 = (const float*)d_in[8];
  const float* b_ih1 = (const float*)d_in[9];
  const float* v_hh1 = (const float*)d_in[10];
  const float* g_hh1 = (const float*)d_in[11];
  const float* b_hh1 = (const float*)d_in[12];
  const float* w_fc  = (const float*)d_in[13];
  const float* b_fc  = (const float*)d_in[14];
  float* out = (float*)d_out;

  char* w = (char*)d_ws;
  size_t off = 0;
  auto alloc = [&](size_t bytes) -> char* {
    char* p = w + off; off += (bytes + 255) & ~(size_t)255; return p;
  };
  int*   flags  = (int*)alloc(4096 + 256);   // 8 groups x 128 ints, then claim[8]
  int*   claim  = flags + 1024;
  float* h1fin  = (float*)alloc((size_t)256 * 512 * 4);
  u16*   h0ring = (u16*)alloc((size_t)8 * BH * 2);
  u16*   h1ring = (u16*)alloc((size_t)4 * BH * 2);
  u16*   xb     = (u16*)alloc((size_t)B_SZ * T_SZ * IN_SZ * 2);
  u16*   wih0   = (u16*)alloc((size_t)G3 * IN_SZ * 2);
  u16*   whh0   = (u16*)alloc((size_t)G3 * H_SZ * 2);
  u16*   wih1   = (u16*)alloc((size_t)G3 * H_SZ * 2);
  u16*   whh1   = (u16*)alloc((size_t)G3 * H_SZ * 2);
  if (off > ws_size) return;  // ~18MB; evidenced ws is far larger

  hipMemsetAsync(flags, 0, 4096 + 256, stream);
  norm_cast_kernel<<<384, 256, 0, stream>>>(v_ih0, g_ih0, wih0, IN_SZ);
  norm_cast_kernel<<<384, 256, 0, stream>>>(v_hh0, g_hh0, whh0, H_SZ);
  norm_cast_kernel<<<384, 256, 0, stream>>>(v_ih1, g_ih1, wih1, H_SZ);
  norm_cast_kernel<<<384, 256, 0, stream>>>(v_hh1, g_hh1, whh1, H_SZ);
  castx_kernel<<<4096, 256, 0, stream>>>(x, xb);

  fused_rnn_kernel<<<256, 256, 0, stream>>>(whh0, wih0, b_ih0, b_hh0,
                                            whh1, wih1, b_ih1, b_hh1,
                                            xb, h0ring, h1ring, h1fin,
                                            flags, claim);
  fc_kernel<<<256, 256, 0, stream>>>(h1fin, w_fc, b_fc, out);
}